// Round 9
// baseline (224.262 us; speedup 1.0000x reference)
//
#include <hip/hip_runtime.h>
#include <hip/hip_bf16.h>

#define N_FINE   16384
#define S_COARSE 4096
#define DC       256
#define DF       64
#define K1       320   // DC + DF
#define C1       256
#define C2       128
#define BIGF     1e8f
#define EPS_W    1e-8f
#define EPS_BN   1e-5f
#define IMAX     0x7fffffff

typedef __attribute__((ext_vector_type(8))) short bf16x8;
typedef __attribute__((ext_vector_type(8))) unsigned short u16x8;
typedef __attribute__((ext_vector_type(4))) float f32x4;

// ---------------- workspace layout (bytes) ----------------
#define OFF_CNT    128        // 2 ints: gemm1 / gemm2 completion counters
#define OFF_RANGES 0          // 8 ints
#define OFF_SUMS   256        // sums1[256] sumsq1[256] sums2[128] sumsq2[128]
#define OFF_SCALE1 3328
#define OFF_SHIFT1 4352
#define OFF_SCALE2 5376
#define OFF_SHIFT2 5888
#define OFF_CPACK  8192       // 4096 * float4
#define OFF_CFT    73728      // 4096*256*4 = 4 MiB
#define OFF_IDX3   4268032    // 16384*3 int
#define OFF_W3     4464640    // 16384*3 f
#define OFF_W1B    4661248    // 256*320*2 = 160 KiB (bf16)
#define OFF_W2B    4825088    // 128*256*2 = 64 KiB (bf16)
#define OFF_Y1     4890624    // 16384*256*2 = 8 MiB (bf16)
#define OFF_Y2     13279232   // 16384*128*4 = 8 MiB (f32)

__device__ inline unsigned short f2bf_bits(float f) {
    __hip_bfloat16 h = __float2bfloat16(f);
    unsigned short u;
    __builtin_memcpy(&u, &h, 2);
    return u;
}

// ---------------- fused setup: range | zero sums+cnt | pack | cvtw | transpose ----------------
// blocks: 0 = range+zero, 1..16 = pack, 17..336 = cvtw, 337..1360 = transpose_cf
__global__ __launch_bounds__(256) void setup_kernel(
    const int* __restrict__ cid, int* __restrict__ ranges, float* __restrict__ sums,
    int* __restrict__ cnt,
    const float* __restrict__ cxyz, float4* __restrict__ cpack,
    const float* __restrict__ W1, const float* __restrict__ W2,
    unsigned short* __restrict__ W1b, unsigned short* __restrict__ W2b,
    const float* __restrict__ cf, float* __restrict__ cfT)
{
    __shared__ float tile[32][33];
    int b = blockIdx.x, t = threadIdx.x;
    if (b == 0) {
        if (t < 8) ranges[t] = 0;
        if (t < 2) cnt[t] = 0;
        for (int i = t; i < 768; i += 256) sums[i] = 0.f;
        __syncthreads();
        for (int s = t; s < S_COARSE; s += 256) {
            int c = cid[s];
            if (s == 0 || cid[s - 1] != c) ranges[c] = s;
            if (s == S_COARSE - 1 || cid[s + 1] != c) ranges[4 + c] = s + 1;
        }
    } else if (b <= 16) {
        int s = (b - 1) * 256 + t;
        float x = cxyz[s], y = cxyz[S_COARSE + s], z = cxyz[2 * S_COARSE + s];
        cpack[s] = make_float4(x, y, z, x * x + y * y + z * z);
    } else if (b <= 336) {
        int i = (b - 17) * 256 + t;     // covers 81920 = C1*K1; C2*C1=32768 subset
        W1b[i] = f2bf_bits(W1[i]);
        if (i < C2 * C1) W2b[i] = f2bf_bits(W2[i]);
    } else {
        int lb = b - 337;                // 1024 transpose blocks
        int tx = t & 31, ty = t >> 5;
        int s0 = (lb & 127) * 32, c0 = (lb >> 7) * 32;
        #pragma unroll
        for (int i = 0; i < 4; i++)
            tile[ty + i * 8][tx] = cf[(c0 + ty + i * 8) * S_COARSE + s0 + tx];
        __syncthreads();
        #pragma unroll
        for (int i = 0; i < 4; i++) {
            int s = ty + i * 8;
            cfT[(s0 + s) * DC + c0 + tx] = tile[tx][s];
        }
    }
}

// ---------------- 3-NN: one wave per fine point, (d,idx)-lex selection ----------------
// Lane l scans candidates st+l, st+l+64, ... (coalesced float4); local top-3 via
// strict-< insert (ascending idx per lane => lex-ordered). Butterfly shfl_xor merge
// with explicit lexicographic comparator == jax top_k stable tie-breaking.
__global__ __launch_bounds__(256) void knn_kernel(const float* __restrict__ fxyz,
                                                  const int* __restrict__ fpid,
                                                  const float4* __restrict__ cpack,
                                                  const int* __restrict__ ranges,
                                                  int* __restrict__ idx3,
                                                  float* __restrict__ w3) {
    int t = threadIdx.x;
    int lane = t & 63, wid = t >> 6;
    int n = blockIdx.x * 4 + wid;
    int fid = fpid[n];
    float fx = fxyz[n], fy = fxyz[N_FINE + n], fz = fxyz[2 * N_FINE + n];
    float fn2 = fx * fx + fy * fy + fz * fz;
    int st = ranges[fid], en = ranges[4 + fid];

    float d0 = BIGF, d1 = BIGF, d2v = BIGF;
    int i0 = IMAX, i1 = IMAX, i2 = IMAX;
    for (int s = st + lane; s < en; s += 64) {
        float4 c = cpack[s];
        float d = fn2 + c.w - 2.0f * (fx * c.x + fy * c.y + fz * c.z);
        if (d < d0)       { d2v = d1; i2 = i1; d1 = d0; i1 = i0; d0 = d; i0 = s; }
        else if (d < d1)  { d2v = d1; i2 = i1; d1 = d;  i1 = s; }
        else if (d < d2v) { d2v = d;  i2 = s; }
    }
    // butterfly all-reduce merge across the wave
    #pragma unroll
    for (int m = 1; m < 64; m <<= 1) {
        float e0 = __shfl_xor(d0, m, 64), e1 = __shfl_xor(d1, m, 64), e2 = __shfl_xor(d2v, m, 64);
        int   j0 = __shfl_xor(i0, m, 64), j1 = __shfl_xor(i1, m, 64), j2 = __shfl_xor(i2, m, 64);
        // insert (e0,j0),(e1,j1),(e2,j2) (sorted) with lex compare
        #pragma unroll
        for (int q = 0; q < 3; q++) {
            float e = (q == 0) ? e0 : (q == 1) ? e1 : e2;
            int   j = (q == 0) ? j0 : (q == 1) ? j1 : j2;
            bool b0 = (e < d0) || (e == d0 && j < i0);
            bool b1 = (e < d1) || (e == d1 && j < i1);
            bool b2 = (e < d2v) || (e == d2v && j < i2);
            if (b0)      { d2v = d1; i2 = i1; d1 = d0; i1 = i0; d0 = e; i0 = j; }
            else if (b1) { d2v = d1; i2 = i1; d1 = e;  i1 = j; }
            else if (b2) { d2v = e;  i2 = j; }
        }
    }
    if (lane == 0) {
        // fewer than 3 in-piece candidates: fill with lowest masked indices (all BIG),
        // matching top_k stability on the all-BIG masked row.
        int cand = 0;
        while (i0 == IMAX || i1 == IMAX || i2 == IMAX) {
            if (cand >= st && cand < en) { cand = en; continue; }
            if (i0 == IMAX)      { i0 = cand; d0 = BIGF; }
            else if (i1 == IMAX) { i1 = cand; d1 = BIGF; }
            else                 { i2 = cand; d2v = BIGF; }
            cand++;
        }
        float w0 = 1.0f / (d0 + EPS_W);
        float w1 = 1.0f / (d1 + EPS_W);
        float w2 = 1.0f / (d2v + EPS_W);
        float inv = 1.0f / (w0 + w1 + w2);
        idx3[n * 3 + 0] = i0; idx3[n * 3 + 1] = i1; idx3[n * 3 + 2] = i2;
        w3[n * 3 + 0] = w0 * inv; w3[n * 3 + 1] = w1 * inv; w3[n * 3 + 2] = w2 * inv;
    }
}

// ---------------- fused interp + GEMM1 + stats + tail finalize1 ----------------
// BM=32, BN=256 (full output width, interp computed once), grid (512,1), 4 waves.
__global__ __launch_bounds__(256) void gemm1_kernel(
    const int* __restrict__ idx3, const float* __restrict__ w3,
    const float* __restrict__ cfT, const float* __restrict__ ff,
    const unsigned short* __restrict__ W1b, const float* __restrict__ bias,
    unsigned short* __restrict__ Y1, float* __restrict__ sums, float* __restrict__ sumsq,
    const float* __restrict__ g, const float* __restrict__ be,
    float* __restrict__ scale, float* __restrict__ shift, int* __restrict__ cnt)
{
    __shared__ __align__(16) unsigned short As[4 * 32 * 8];   // 2 KiB
    __shared__ __align__(16) unsigned short Bs[4 * 256 * 8];  // 16 KiB
    __shared__ int   sI[32][3];
    __shared__ float sWt[32][3];
    __shared__ int isLast;
    int t = threadIdx.x;
    int m0 = blockIdx.x * 32;
    int lane = t & 63, wid = t >> 6;
    int wn = wid * 64;

    if (t < 32) {
        sI[t][0]  = idx3[(m0 + t) * 3 + 0];
        sI[t][1]  = idx3[(m0 + t) * 3 + 1];
        sI[t][2]  = idx3[(m0 + t) * 3 + 2];
        sWt[t][0] = w3[(m0 + t) * 3 + 0];
        sWt[t][1] = w3[(m0 + t) * 3 + 1];
        sWt[t][2] = w3[(m0 + t) * 3 + 2];
    }
    int ksA = t & 3, rowA = t >> 2;          // A staging: threads 0..127
    int fxw = ksA << 2;
    int gA = ksA * 32 + (rowA ^ fxw);
    int rowB = t;                             // B staging: each thread one W1 row
    f32x4 acc[2][4] = {};
    int ks = lane >> 4, r16 = lane & 15, fxr = ks << 2;
    __syncthreads();

    for (int kt = 0; kt < K1; kt += 32) {
        u16x8 va;
        if (t < 128) {
            int k0 = kt + ksA * 8;
            if (k0 < DC) {
                int i0 = sI[rowA][0], i1 = sI[rowA][1], i2 = sI[rowA][2];
                float w0 = sWt[rowA][0], w1 = sWt[rowA][1], w2 = sWt[rowA][2];
                const float* c0p = &cfT[i0 * DC + k0];
                const float* c1p = &cfT[i1 * DC + k0];
                const float* c2p = &cfT[i2 * DC + k0];
                float4 a0 = *(const float4*)c0p, a1 = *(const float4*)(c0p + 4);
                float4 b0 = *(const float4*)c1p, b1 = *(const float4*)(c1p + 4);
                float4 e0 = *(const float4*)c2p, e1 = *(const float4*)(c2p + 4);
                va[0] = f2bf_bits(w0 * a0.x + w1 * b0.x + w2 * e0.x);
                va[1] = f2bf_bits(w0 * a0.y + w1 * b0.y + w2 * e0.y);
                va[2] = f2bf_bits(w0 * a0.z + w1 * b0.z + w2 * e0.z);
                va[3] = f2bf_bits(w0 * a0.w + w1 * b0.w + w2 * e0.w);
                va[4] = f2bf_bits(w0 * a1.x + w1 * b1.x + w2 * e1.x);
                va[5] = f2bf_bits(w0 * a1.y + w1 * b1.y + w2 * e1.y);
                va[6] = f2bf_bits(w0 * a1.z + w1 * b1.z + w2 * e1.z);
                va[7] = f2bf_bits(w0 * a1.w + w1 * b1.w + w2 * e1.w);
            } else {
                int c = k0 - DC;   // fine-feature channels c..c+7
                #pragma unroll
                for (int i = 0; i < 8; i++)
                    va[i] = f2bf_bits(ff[(c + i) * N_FINE + m0 + rowA]);
            }
        }
        u16x8 vb[4];
        #pragma unroll
        for (int kb = 0; kb < 4; kb++)
            vb[kb] = *(const u16x8*)&W1b[(size_t)rowB * K1 + kt + kb * 8];
        __syncthreads();   // previous iteration's frag reads complete
        if (t < 128) *(u16x8*)&As[gA * 8] = va;
        #pragma unroll
        for (int kb = 0; kb < 4; kb++)
            *(u16x8*)&Bs[(kb * 256 + (rowB ^ (kb << 2))) * 8] = vb[kb];
        __syncthreads();
        bf16x8 af[2], bfr[4];
        #pragma unroll
        for (int mi = 0; mi < 2; mi++)
            af[mi] = *(const bf16x8*)&As[(ks * 32 + ((mi * 16 + r16) ^ fxr)) * 8];
        #pragma unroll
        for (int nj = 0; nj < 4; nj++)
            bfr[nj] = *(const bf16x8*)&Bs[(ks * 256 + ((wn + nj * 16 + r16) ^ fxr)) * 8];
        #pragma unroll
        for (int mi = 0; mi < 2; mi++)
            #pragma unroll
            for (int nj = 0; nj < 4; nj++)
                acc[mi][nj] = __builtin_amdgcn_mfma_f32_16x16x32_bf16(af[mi], bfr[nj], acc[mi][nj], 0, 0, 0);
    }

    // epilogue: C/D layout col(n)=lane&15, row(m)=4*(lane>>4)+reg  [m89/m91]
    float sl[4] = {0.f, 0.f, 0.f, 0.f}, s2l[4] = {0.f, 0.f, 0.f, 0.f};
    #pragma unroll
    for (int nj = 0; nj < 4; nj++) {
        int n = wn + nj * 16 + r16;
        float bb = bias[n];
        #pragma unroll
        for (int mi = 0; mi < 2; mi++) {
            #pragma unroll
            for (int r = 0; r < 4; r++) {
                int m = m0 + mi * 16 + ks * 4 + r;
                float o = acc[mi][nj][r] + bb;
                Y1[(size_t)m * C1 + n] = f2bf_bits(o);
                sl[nj] += o; s2l[nj] += o * o;
            }
        }
    }
    #pragma unroll
    for (int nj = 0; nj < 4; nj++) {
        sl[nj]  += __shfl_xor(sl[nj],  16, 64);
        sl[nj]  += __shfl_xor(sl[nj],  32, 64);
        s2l[nj] += __shfl_xor(s2l[nj], 16, 64);
        s2l[nj] += __shfl_xor(s2l[nj], 32, 64);
    }
    if (lane < 16) {
        #pragma unroll
        for (int nj = 0; nj < 4; nj++) {
            atomicAdd(&sums[wn + nj * 16 + lane],  sl[nj]);
            atomicAdd(&sumsq[wn + nj * 16 + lane], s2l[nj]);
        }
    }
    // -------- tail finalize (last block computes BN1 scale/shift) --------
    __threadfence();
    __syncthreads();
    if (t == 0) isLast = (atomicAdd(cnt, 1) == (int)gridDim.x - 1);
    __syncthreads();
    if (isLast && t < C1) {
        float s  = atomicAdd(&sums[t], 0.f);     // coherent L2 read
        float s2 = atomicAdd(&sumsq[t], 0.f);
        float mean = s * (1.0f / N_FINE);
        float var = s2 * (1.0f / N_FINE) - mean * mean;
        float sc = g[t] * rsqrtf(var + EPS_BN);
        scale[t] = sc;
        shift[t] = be[t] - mean * sc;
    }
}

// ---------------- bf16 MFMA GEMM2 (BN1+ReLU on A, f32 out, stats + tail finalize2) ----------------
// BM=128, BN=64, 256 threads = 4 waves (2M x 2N).
template <int KDIM, int NOUT>
__global__ __launch_bounds__(256) void mfma_gemm2_kernel(
    const unsigned short* __restrict__ A,   // [M][KDIM] bf16 bits
    const unsigned short* __restrict__ B,   // [NOUT][KDIM] bf16 bits
    const float* __restrict__ bias,
    const float* __restrict__ scale,
    const float* __restrict__ shift,
    float* __restrict__ Yout,
    float* __restrict__ sums, float* __restrict__ sumsq,
    const float* __restrict__ g, const float* __restrict__ be,
    float* __restrict__ scale2, float* __restrict__ shift2, int* __restrict__ cnt)
{
    __shared__ __align__(16) unsigned short As[4 * 128 * 8];  // 8 KiB
    __shared__ __align__(16) unsigned short Bs[4 * 64 * 8];   // 4 KiB
    __shared__ int isLast;
    int t = threadIdx.x;
    int m0 = blockIdx.x * 128, j0 = blockIdx.y * 64;
    int lane = t & 63, wid = t >> 6;
    int wm = (wid >> 1) * 64, wn = (wid & 1) * 32;

    int ksA = t & 3;
    int rowA0 = t >> 2;
    int rowA1 = 64 + rowA0;
    int fxw = ksA << 2;
    int gA0 = ksA * 128 + (rowA0 ^ fxw);
    int gA1 = ksA * 128 + (rowA1 ^ fxw);
    int gB  = ksA * 64 + (rowA0 ^ fxw);
    const unsigned short* pa0 = A + (size_t)(m0 + rowA0) * KDIM + ksA * 8;
    const unsigned short* pa1 = A + (size_t)(m0 + rowA1) * KDIM + ksA * 8;
    const unsigned short* pb  = B + (size_t)(j0 + rowA0) * KDIM + ksA * 8;

    f32x4 acc[4][2] = {};
    int ks = lane >> 4, r16 = lane & 15;
    int fxr = ks << 2;

    for (int kt = 0; kt < KDIM; kt += 32) {
        u16x8 va0 = *(const u16x8*)(pa0 + kt);
        u16x8 va1 = *(const u16x8*)(pa1 + kt);
        u16x8 vb  = *(const u16x8*)(pb + kt);
        int kb = kt + ksA * 8;
        #pragma unroll
        for (int i = 0; i < 8; i++) {
            float sc = scale[kb + i], sh = shift[kb + i];
            float f0 = __uint_as_float(((unsigned)va0[i]) << 16);
            float f1 = __uint_as_float(((unsigned)va1[i]) << 16);
            va0[i] = f2bf_bits(fmaxf(fmaf(f0, sc, sh), 0.f));
            va1[i] = f2bf_bits(fmaxf(fmaf(f1, sc, sh), 0.f));
        }
        __syncthreads();
        *(u16x8*)&As[gA0 * 8] = va0;
        *(u16x8*)&As[gA1 * 8] = va1;
        *(u16x8*)&Bs[gB * 8]  = vb;
        __syncthreads();
        bf16x8 af[4], bfr[2];
        #pragma unroll
        for (int mi = 0; mi < 4; mi++)
            af[mi] = *(const bf16x8*)&As[(ks * 128 + wm + mi * 16 + (r16 ^ fxr)) * 8];
        #pragma unroll
        for (int nj = 0; nj < 2; nj++)
            bfr[nj] = *(const bf16x8*)&Bs[(ks * 64 + wn + nj * 16 + (r16 ^ fxr)) * 8];
        #pragma unroll
        for (int mi = 0; mi < 4; mi++)
            #pragma unroll
            for (int nj = 0; nj < 2; nj++)
                acc[mi][nj] = __builtin_amdgcn_mfma_f32_16x16x32_bf16(af[mi], bfr[nj], acc[mi][nj], 0, 0, 0);
    }

    float sl[2] = {0.f, 0.f}, s2l[2] = {0.f, 0.f};
    #pragma unroll
    for (int nj = 0; nj < 2; nj++) {
        int n = j0 + wn + nj * 16 + r16;
        float bb = bias[n];
        #pragma unroll
        for (int mi = 0; mi < 4; mi++) {
            #pragma unroll
            for (int r = 0; r < 4; r++) {
                int m = m0 + wm + mi * 16 + ks * 4 + r;
                float o = acc[mi][nj][r] + bb;
                Yout[(size_t)m * NOUT + n] = o;
                sl[nj] += o; s2l[nj] += o * o;
            }
        }
    }
    #pragma unroll
    for (int nj = 0; nj < 2; nj++) {
        sl[nj]  += __shfl_xor(sl[nj],  16, 64);
        sl[nj]  += __shfl_xor(sl[nj],  32, 64);
        s2l[nj] += __shfl_xor(s2l[nj], 16, 64);
        s2l[nj] += __shfl_xor(s2l[nj], 32, 64);
    }
    if (lane < 16) {
        atomicAdd(&sums[j0 + wn + lane],       sl[0]);
        atomicAdd(&sums[j0 + wn + 16 + lane],  sl[1]);
        atomicAdd(&sumsq[j0 + wn + lane],      s2l[0]);
        atomicAdd(&sumsq[j0 + wn + 16 + lane], s2l[1]);
    }
    // -------- tail finalize (last block computes BN2 scale/shift) --------
    __threadfence();
    __syncthreads();
    if (t == 0) isLast = (atomicAdd(cnt, 1) == (int)(gridDim.x * gridDim.y) - 1);
    __syncthreads();
    if (isLast && t < NOUT) {
        float s  = atomicAdd(&sums[t], 0.f);
        float s2 = atomicAdd(&sumsq[t], 0.f);
        float mean = s * (1.0f / N_FINE);
        float var = s2 * (1.0f / N_FINE) - mean * mean;
        float sc = g[t] * rsqrtf(var + EPS_BN);
        scale2[t] = sc;
        shift2[t] = be[t] - mean * sc;
    }
}

// ---------------- BN2+ReLU fused transposed store: out[c][n] ----------------
__global__ __launch_bounds__(256) void out_kernel(const float* __restrict__ Y2,
                                                  const float* __restrict__ scale2,
                                                  const float* __restrict__ shift2,
                                                  float* __restrict__ out) {
    __shared__ float tile[64][65];
    int t = threadIdx.x;
    int n0 = blockIdx.x * 64, c0 = blockIdx.y * 64;
    int cl = t & 63, rg = t >> 6;
    #pragma unroll
    for (int i = 0; i < 16; i++) {
        int r = rg + i * 4;
        tile[r][cl] = Y2[(n0 + r) * C2 + c0 + cl];
    }
    __syncthreads();
    #pragma unroll
    for (int i = 0; i < 16; i++) {
        int c = rg + i * 4;
        float v = fmaf(tile[cl][c], scale2[c0 + c], shift2[c0 + c]);
        out[(c0 + c) * N_FINE + n0 + cl] = fmaxf(v, 0.f);
    }
}

extern "C" void kernel_launch(void* const* d_in, const int* in_sizes, int n_in,
                              void* d_out, int out_size, void* d_ws, size_t ws_size,
                              hipStream_t stream) {
    const float* fine_xyz   = (const float*)d_in[0];
    const float* coarse_xyz = (const float*)d_in[1];
    const int*   fine_pid   = (const int*)d_in[2];
    const int*   coarse_pid = (const int*)d_in[3];
    const float* fine_feat  = (const float*)d_in[4];
    const float* coarse_feat= (const float*)d_in[5];
    const float* W1  = (const float*)d_in[6];
    const float* b1  = (const float*)d_in[7];
    const float* g1  = (const float*)d_in[8];
    const float* be1 = (const float*)d_in[9];
    const float* W2  = (const float*)d_in[10];
    const float* b2  = (const float*)d_in[11];
    const float* g2  = (const float*)d_in[12];
    const float* be2 = (const float*)d_in[13];
    float* out = (float*)d_out;

    char* ws = (char*)d_ws;
    int*    ranges = (int*)(ws + OFF_RANGES);
    int*    cnt    = (int*)(ws + OFF_CNT);
    float*  sums1  = (float*)(ws + OFF_SUMS);
    float*  sumsq1 = sums1 + 256;
    float*  sums2  = sums1 + 512;
    float*  sumsq2 = sums1 + 640;
    float*  scale1 = (float*)(ws + OFF_SCALE1);
    float*  shift1 = (float*)(ws + OFF_SHIFT1);
    float*  scale2 = (float*)(ws + OFF_SCALE2);
    float*  shift2 = (float*)(ws + OFF_SHIFT2);
    float4* cpack  = (float4*)(ws + OFF_CPACK);
    float*  cfT    = (float*)(ws + OFF_CFT);
    int*    idx3   = (int*)(ws + OFF_IDX3);
    float*  w3     = (float*)(ws + OFF_W3);
    unsigned short* W1b = (unsigned short*)(ws + OFF_W1B);
    unsigned short* W2b = (unsigned short*)(ws + OFF_W2B);
    unsigned short* Y1  = (unsigned short*)(ws + OFF_Y1);
    float*          Y2  = (float*)(ws + OFF_Y2);

    setup_kernel<<<1361, 256, 0, stream>>>(coarse_pid, ranges, sums1, cnt,
                                           coarse_xyz, cpack, W1, W2, W1b, W2b,
                                           coarse_feat, cfT);
    knn_kernel<<<N_FINE / 4, 256, 0, stream>>>(fine_xyz, fine_pid, cpack, ranges, idx3, w3);

    gemm1_kernel<<<N_FINE / 32, 256, 0, stream>>>(idx3, w3, cfT, fine_feat,
                                                  W1b, b1, Y1, sums1, sumsq1,
                                                  g1, be1, scale1, shift1, cnt);

    mfma_gemm2_kernel<C1, C2><<<dim3(N_FINE / 128, C2 / 64), 256, 0, stream>>>(
        Y1, W2b, b2, scale1, shift1, Y2, sums2, sumsq2,
        g2, be2, scale2, shift2, cnt + 1);

    out_kernel<<<dim3(N_FINE / 64, C2 / 64), 256, 0, stream>>>(Y2, scale2, shift2, out);
}

// Round 11
// 180.606 us; speedup vs baseline: 1.2417x; 1.2417x over previous
//
#include <hip/hip_runtime.h>
#include <hip/hip_bf16.h>

#define N_FINE   16384
#define S_COARSE 4096
#define DC       256
#define DF       64
#define K1       320   // DC + DF
#define C1       256
#define C2       128
#define BIGF     1e8f
#define EPS_W    1e-8f
#define EPS_BN   1e-5f
#define IMAX     0x7fffffff

typedef __attribute__((ext_vector_type(8))) short bf16x8;
typedef __attribute__((ext_vector_type(8))) unsigned short u16x8;
typedef __attribute__((ext_vector_type(4))) float f32x4;

// ---------------- workspace layout (bytes) ----------------
#define OFF_RANGES 0          // 8 ints
#define OFF_SUMS   256        // sums1[256] sumsq1[256] sums2[128] sumsq2[128]
#define OFF_SCALE1 3328
#define OFF_SHIFT1 4352
#define OFF_SCALE2 5376
#define OFF_SHIFT2 5888
#define OFF_CPACK  8192       // 4096 * float4
#define OFF_CFT    73728      // 4096*256*4 = 4 MiB
#define OFF_IDX3   4268032    // 16384*3 int
#define OFF_W3     4464640    // 16384*3 f
#define OFF_W1B    4661248    // 256*320*2 = 160 KiB (bf16)
#define OFF_W2B    4825088    // 128*256*2 = 64 KiB (bf16)
#define OFF_Y1     4890624    // 16384*256*2 = 8 MiB (bf16)
#define OFF_Y2     13279232   // 16384*128*4 = 8 MiB (f32)

__device__ inline unsigned short f2bf_bits(float f) {
    __hip_bfloat16 h = __float2bfloat16(f);
    unsigned short u;
    __builtin_memcpy(&u, &h, 2);
    return u;
}
__device__ inline float bf2f(unsigned short u) {
    return __uint_as_float(((unsigned)u) << 16);
}

// ---------------- fused setup: range | zero sums | pack | cvtw | transpose ----------------
__global__ __launch_bounds__(256) void setup_kernel(
    const int* __restrict__ cid, int* __restrict__ ranges, float* __restrict__ sums,
    const float* __restrict__ cxyz, float4* __restrict__ cpack,
    const float* __restrict__ W1, const float* __restrict__ W2,
    unsigned short* __restrict__ W1b, unsigned short* __restrict__ W2b,
    const float* __restrict__ cf, float* __restrict__ cfT)
{
    __shared__ float tile[32][33];
    int b = blockIdx.x, t = threadIdx.x;
    if (b == 0) {
        if (t < 8) ranges[t] = 0;
        for (int i = t; i < 768; i += 256) sums[i] = 0.f;
        __syncthreads();
        for (int s = t; s < S_COARSE; s += 256) {
            int c = cid[s];
            if (s == 0 || cid[s - 1] != c) ranges[c] = s;
            if (s == S_COARSE - 1 || cid[s + 1] != c) ranges[4 + c] = s + 1;
        }
    } else if (b <= 16) {
        int s = (b - 1) * 256 + t;
        float x = cxyz[s], y = cxyz[S_COARSE + s], z = cxyz[2 * S_COARSE + s];
        cpack[s] = make_float4(x, y, z, x * x + y * y + z * z);
    } else if (b <= 336) {
        int i = (b - 17) * 256 + t;
        W1b[i] = f2bf_bits(W1[i]);
        if (i < C2 * C1) W2b[i] = f2bf_bits(W2[i]);
    } else {
        int lb = b - 337;
        int tx = t & 31, ty = t >> 5;
        int s0 = (lb & 127) * 32, c0 = (lb >> 7) * 32;
        #pragma unroll
        for (int i = 0; i < 4; i++)
            tile[ty + i * 8][tx] = cf[(c0 + ty + i * 8) * S_COARSE + s0 + tx];
        __syncthreads();
        #pragma unroll
        for (int i = 0; i < 4; i++) {
            int s = ty + i * 8;
            cfT[(s0 + s) * DC + c0 + tx] = tile[tx][s];
        }
    }
}

// ---------------- 3-NN: one wave per fine point, (d,idx)-lex selection ----------------
__global__ __launch_bounds__(256) void knn_kernel(const float* __restrict__ fxyz,
                                                  const int* __restrict__ fpid,
                                                  const float4* __restrict__ cpack,
                                                  const int* __restrict__ ranges,
                                                  int* __restrict__ idx3,
                                                  float* __restrict__ w3) {
    int t = threadIdx.x;
    int lane = t & 63, wid = t >> 6;
    int n = blockIdx.x * 4 + wid;
    int fid = fpid[n];
    float fx = fxyz[n], fy = fxyz[N_FINE + n], fz = fxyz[2 * N_FINE + n];
    float fn2 = fx * fx + fy * fy + fz * fz;
    int st = ranges[fid], en = ranges[4 + fid];

    float d0 = BIGF, d1 = BIGF, d2v = BIGF;
    int i0 = IMAX, i1 = IMAX, i2 = IMAX;
    for (int s = st + lane; s < en; s += 64) {
        float4 c = cpack[s];
        float d = fn2 + c.w - 2.0f * (fx * c.x + fy * c.y + fz * c.z);
        if (d < d0)       { d2v = d1; i2 = i1; d1 = d0; i1 = i0; d0 = d; i0 = s; }
        else if (d < d1)  { d2v = d1; i2 = i1; d1 = d;  i1 = s; }
        else if (d < d2v) { d2v = d;  i2 = s; }
    }
    #pragma unroll
    for (int m = 1; m < 64; m <<= 1) {
        float e0 = __shfl_xor(d0, m, 64), e1 = __shfl_xor(d1, m, 64), e2 = __shfl_xor(d2v, m, 64);
        int   j0 = __shfl_xor(i0, m, 64), j1 = __shfl_xor(i1, m, 64), j2 = __shfl_xor(i2, m, 64);
        #pragma unroll
        for (int q = 0; q < 3; q++) {
            float e = (q == 0) ? e0 : (q == 1) ? e1 : e2;
            int   j = (q == 0) ? j0 : (q == 1) ? j1 : j2;
            bool b0 = (e < d0) || (e == d0 && j < i0);
            bool b1 = (e < d1) || (e == d1 && j < i1);
            bool b2 = (e < d2v) || (e == d2v && j < i2);
            if (b0)      { d2v = d1; i2 = i1; d1 = d0; i1 = i0; d0 = e; i0 = j; }
            else if (b1) { d2v = d1; i2 = i1; d1 = e;  i1 = j; }
            else if (b2) { d2v = e;  i2 = j; }
        }
    }
    if (lane == 0) {
        int cand = 0;
        while (i0 == IMAX || i1 == IMAX || i2 == IMAX) {
            if (cand >= st && cand < en) { cand = en; continue; }
            if (i0 == IMAX)      { i0 = cand; d0 = BIGF; }
            else if (i1 == IMAX) { i1 = cand; d1 = BIGF; }
            else                 { i2 = cand; d2v = BIGF; }
            cand++;
        }
        float w0 = 1.0f / (d0 + EPS_W);
        float w1 = 1.0f / (d1 + EPS_W);
        float w2 = 1.0f / (d2v + EPS_W);
        float inv = 1.0f / (w0 + w1 + w2);
        idx3[n * 3 + 0] = i0; idx3[n * 3 + 1] = i1; idx3[n * 3 + 2] = i2;
        w3[n * 3 + 0] = w0 * inv; w3[n * 3 + 1] = w1 * inv; w3[n * 3 + 2] = w2 * inv;
    }
}

// ---------------- fused interp + GEMM1 + stats (software-pipelined staging) ----------------
// BM=32, BN=256, grid 512, 4 waves. Gather bases hoisted; iteration k+1's raw global
// loads issued before iteration k's barriers/MFMA so L2 latency hides under compute.
__global__ __launch_bounds__(256) void gemm1_kernel(
    const int* __restrict__ idx3, const float* __restrict__ w3,
    const float* __restrict__ cfT, const float* __restrict__ ff,
    const unsigned short* __restrict__ W1b, const float* __restrict__ bias,
    unsigned short* __restrict__ Y1, float* __restrict__ sums, float* __restrict__ sumsq)
{
    __shared__ __align__(16) unsigned short As[4 * 32 * 8];   // 2 KiB
    __shared__ __align__(16) unsigned short Bs[4 * 256 * 8];  // 16 KiB
    __shared__ int   sI[32][3];
    __shared__ float sWt[32][3];
    int t = threadIdx.x;
    int m0 = blockIdx.x * 32;
    int lane = t & 63, wid = t >> 6;
    int wn = wid * 64;

    if (t < 32) {
        sI[t][0]  = idx3[(m0 + t) * 3 + 0];
        sI[t][1]  = idx3[(m0 + t) * 3 + 1];
        sI[t][2]  = idx3[(m0 + t) * 3 + 2];
        sWt[t][0] = w3[(m0 + t) * 3 + 0];
        sWt[t][1] = w3[(m0 + t) * 3 + 1];
        sWt[t][2] = w3[(m0 + t) * 3 + 2];
    }
    int ksA = t & 3, rowA = t >> 2;          // A staging: threads 0..127
    int fxw = ksA << 2;
    int gA = ksA * 32 + (rowA ^ fxw);
    int rowB = t;                             // B staging: each thread one W1 row
    f32x4 acc[2][4] = {};
    int ks = lane >> 4, r16 = lane & 15, fxr = ks << 2;
    __syncthreads();                          // sI/sWt visible

    // hoist loop-invariant gather bases + weights
    const float *c0p = nullptr, *c1p = nullptr, *c2p = nullptr;
    float w0v = 0.f, w1v = 0.f, w2v = 0.f;
    if (t < 128) {
        c0p = &cfT[sI[rowA][0] * DC];
        c1p = &cfT[sI[rowA][1] * DC];
        c2p = &cfT[sI[rowA][2] * DC];
        w0v = sWt[rowA][0]; w1v = sWt[rowA][1]; w2v = sWt[rowA][2];
    }
    const unsigned short* pb = &W1b[(size_t)rowB * K1];

    float r[24];
    u16x8 vb[4];

    // prologue: issue kt=0 loads
    {
        int k0 = ksA * 8;       // < DC always
        if (t < 128) {
            *(float4*)&r[0]  = *(const float4*)(c0p + k0);
            *(float4*)&r[4]  = *(const float4*)(c0p + k0 + 4);
            *(float4*)&r[8]  = *(const float4*)(c1p + k0);
            *(float4*)&r[12] = *(const float4*)(c1p + k0 + 4);
            *(float4*)&r[16] = *(const float4*)(c2p + k0);
            *(float4*)&r[20] = *(const float4*)(c2p + k0 + 4);
        }
        #pragma unroll
        for (int kb = 0; kb < 4; kb++) vb[kb] = *(const u16x8*)(pb + kb * 8);
    }

    #pragma unroll
    for (int kt = 0; kt < K1; kt += 32) {
        // transform current raw A data (waits on its loads)
        u16x8 va;
        if (t < 128) {
            int k0 = kt + ksA * 8;
            if (k0 < DC) {
                #pragma unroll
                for (int i = 0; i < 8; i++)
                    va[i] = f2bf_bits(w0v * r[i] + w1v * r[8 + i] + w2v * r[16 + i]);
            } else {
                #pragma unroll
                for (int i = 0; i < 8; i++)
                    va[i] = f2bf_bits(r[i]);
            }
        }
        // issue next iteration's raw loads (latency hides under barriers+MFMA below)
        float rn[24];
        u16x8 vbn[4];
        if (kt + 32 < K1) {
            int k0n = kt + 32 + ksA * 8;
            if (t < 128) {
                if (k0n < DC) {
                    *(float4*)&rn[0]  = *(const float4*)(c0p + k0n);
                    *(float4*)&rn[4]  = *(const float4*)(c0p + k0n + 4);
                    *(float4*)&rn[8]  = *(const float4*)(c1p + k0n);
                    *(float4*)&rn[12] = *(const float4*)(c1p + k0n + 4);
                    *(float4*)&rn[16] = *(const float4*)(c2p + k0n);
                    *(float4*)&rn[20] = *(const float4*)(c2p + k0n + 4);
                } else {
                    int c = k0n - DC;
                    #pragma unroll
                    for (int i = 0; i < 8; i++)
                        rn[i] = ff[(size_t)(c + i) * N_FINE + m0 + rowA];
                }
            }
            #pragma unroll
            for (int kb = 0; kb < 4; kb++)
                vbn[kb] = *(const u16x8*)(pb + kt + 32 + kb * 8);
        }
        __syncthreads();   // previous iteration's frag reads complete
        if (t < 128) *(u16x8*)&As[gA * 8] = va;
        #pragma unroll
        for (int kb = 0; kb < 4; kb++)
            *(u16x8*)&Bs[(kb * 256 + (rowB ^ (kb << 2))) * 8] = vb[kb];
        __syncthreads();
        bf16x8 af[2], bfr[4];
        #pragma unroll
        for (int mi = 0; mi < 2; mi++)
            af[mi] = *(const bf16x8*)&As[(ks * 32 + ((mi * 16 + r16) ^ fxr)) * 8];
        #pragma unroll
        for (int nj = 0; nj < 4; nj++)
            bfr[nj] = *(const bf16x8*)&Bs[(ks * 256 + ((wn + nj * 16 + r16) ^ fxr)) * 8];
        #pragma unroll
        for (int mi = 0; mi < 2; mi++)
            #pragma unroll
            for (int nj = 0; nj < 4; nj++)
                acc[mi][nj] = __builtin_amdgcn_mfma_f32_16x16x32_bf16(af[mi], bfr[nj], acc[mi][nj], 0, 0, 0);
        if (kt + 32 < K1) {
            #pragma unroll
            for (int i = 0; i < 24; i++) r[i] = rn[i];
            #pragma unroll
            for (int kb = 0; kb < 4; kb++) vb[kb] = vbn[kb];
        }
    }

    // epilogue: C/D layout col(n)=lane&15, row(m)=4*(lane>>4)+reg  [m89/m91]
    float sl[4] = {0.f, 0.f, 0.f, 0.f}, s2l[4] = {0.f, 0.f, 0.f, 0.f};
    #pragma unroll
    for (int nj = 0; nj < 4; nj++) {
        int n = wn + nj * 16 + r16;
        float bb = bias[n];
        #pragma unroll
        for (int mi = 0; mi < 2; mi++) {
            #pragma unroll
            for (int r4 = 0; r4 < 4; r4++) {
                int m = m0 + mi * 16 + ks * 4 + r4;
                float o = acc[mi][nj][r4] + bb;
                Y1[(size_t)m * C1 + n] = f2bf_bits(o);
                sl[nj] += o; s2l[nj] += o * o;
            }
        }
    }
    #pragma unroll
    for (int nj = 0; nj < 4; nj++) {
        sl[nj]  += __shfl_xor(sl[nj],  16, 64);
        sl[nj]  += __shfl_xor(sl[nj],  32, 64);
        s2l[nj] += __shfl_xor(s2l[nj], 16, 64);
        s2l[nj] += __shfl_xor(s2l[nj], 32, 64);
    }
    if (lane < 16) {
        #pragma unroll
        for (int nj = 0; nj < 4; nj++) {
            atomicAdd(&sums[wn + nj * 16 + lane],  sl[nj]);
            atomicAdd(&sumsq[wn + nj * 16 + lane], s2l[nj]);
        }
    }
}

// ---------------- bf16 MFMA GEMM2 (BN1+ReLU on A, f32 out, fused stats, pipelined) ----------------
// BM=64, BN=64 -> grid (256,2)=512 blocks (2 blocks/CU, was 1). 4 waves (2M x 2N), 32x32/wave.
template <int KDIM, int NOUT>
__global__ __launch_bounds__(256) void mfma_gemm2_kernel(
    const unsigned short* __restrict__ A,   // [M][KDIM] bf16 bits
    const unsigned short* __restrict__ B,   // [NOUT][KDIM] bf16 bits
    const float* __restrict__ bias,
    const float* __restrict__ scale,
    const float* __restrict__ shift,
    float* __restrict__ Yout,
    float* __restrict__ sums, float* __restrict__ sumsq)
{
    __shared__ __align__(16) unsigned short As[4 * 64 * 8];  // 4 KiB
    __shared__ __align__(16) unsigned short Bs[4 * 64 * 8];  // 4 KiB
    int t = threadIdx.x;
    int m0 = blockIdx.x * 64, j0 = blockIdx.y * 64;
    int lane = t & 63, wid = t >> 6;
    int wm = (wid >> 1) * 32, wn = (wid & 1) * 32;

    int ksA = t & 3;
    int rowA = t >> 2;                 // 0..63
    int fxw = ksA << 2;
    int gA = ksA * 64 + (rowA ^ fxw);
    const unsigned short* pa = A + (size_t)(m0 + rowA) * KDIM + ksA * 8;
    const unsigned short* pb = B + (size_t)(j0 + rowA) * KDIM + ksA * 8;

    f32x4 acc[2][2] = {};
    int ks = lane >> 4, r16 = lane & 15;
    int fxr = ks << 2;

    u16x8 va, vb;
    float4 sc0, sc1, sh0, sh1;
    va = *(const u16x8*)pa;
    vb = *(const u16x8*)pb;
    sc0 = *(const float4*)&scale[ksA * 8];
    sc1 = *(const float4*)&scale[ksA * 8 + 4];
    sh0 = *(const float4*)&shift[ksA * 8];
    sh1 = *(const float4*)&shift[ksA * 8 + 4];

    #pragma unroll
    for (int kt = 0; kt < KDIM; kt += 32) {
        // BN1+ReLU transform on current A (waits on its loads)
        u16x8 vat;
        {
            float scv[8] = {sc0.x, sc0.y, sc0.z, sc0.w, sc1.x, sc1.y, sc1.z, sc1.w};
            float shv[8] = {sh0.x, sh0.y, sh0.z, sh0.w, sh1.x, sh1.y, sh1.z, sh1.w};
            #pragma unroll
            for (int i = 0; i < 8; i++)
                vat[i] = f2bf_bits(fmaxf(fmaf(bf2f(va[i]), scv[i], shv[i]), 0.f));
        }
        // issue next iteration's loads
        u16x8 van, vbn;
        float4 sc0n, sc1n, sh0n, sh1n;
        if (kt + 32 < KDIM) {
            van = *(const u16x8*)(pa + kt + 32);
            vbn = *(const u16x8*)(pb + kt + 32);
            int kb = kt + 32 + ksA * 8;
            sc0n = *(const float4*)&scale[kb];
            sc1n = *(const float4*)&scale[kb + 4];
            sh0n = *(const float4*)&shift[kb];
            sh1n = *(const float4*)&shift[kb + 4];
        }
        __syncthreads();
        *(u16x8*)&As[gA * 8] = vat;
        *(u16x8*)&Bs[gA * 8] = vb;
        __syncthreads();
        bf16x8 af[2], bfr[2];
        #pragma unroll
        for (int mi = 0; mi < 2; mi++)
            af[mi] = *(const bf16x8*)&As[(ks * 64 + ((wm + mi * 16 + r16) ^ fxr)) * 8];
        #pragma unroll
        for (int nj = 0; nj < 2; nj++)
            bfr[nj] = *(const bf16x8*)&Bs[(ks * 64 + ((wn + nj * 16 + r16) ^ fxr)) * 8];
        #pragma unroll
        for (int mi = 0; mi < 2; mi++)
            #pragma unroll
            for (int nj = 0; nj < 2; nj++)
                acc[mi][nj] = __builtin_amdgcn_mfma_f32_16x16x32_bf16(af[mi], bfr[nj], acc[mi][nj], 0, 0, 0);
        if (kt + 32 < KDIM) {
            va = van; vb = vbn;
            sc0 = sc0n; sc1 = sc1n; sh0 = sh0n; sh1 = sh1n;
        }
    }

    float sl[2] = {0.f, 0.f}, s2l[2] = {0.f, 0.f};
    #pragma unroll
    for (int nj = 0; nj < 2; nj++) {
        int n = j0 + wn + nj * 16 + r16;
        float bb = bias[n];
        #pragma unroll
        for (int mi = 0; mi < 2; mi++) {
            #pragma unroll
            for (int r4 = 0; r4 < 4; r4++) {
                int m = m0 + wm + mi * 16 + ks * 4 + r4;
                float o = acc[mi][nj][r4] + bb;
                Yout[(size_t)m * NOUT + n] = o;
                sl[nj] += o; s2l[nj] += o * o;
            }
        }
    }
    #pragma unroll
    for (int nj = 0; nj < 2; nj++) {
        sl[nj]  += __shfl_xor(sl[nj],  16, 64);
        sl[nj]  += __shfl_xor(sl[nj],  32, 64);
        s2l[nj] += __shfl_xor(s2l[nj], 16, 64);
        s2l[nj] += __shfl_xor(s2l[nj], 32, 64);
    }
    if (lane < 16) {
        atomicAdd(&sums[j0 + wn + lane],       sl[0]);
        atomicAdd(&sums[j0 + wn + 16 + lane],  sl[1]);
        atomicAdd(&sumsq[j0 + wn + lane],      s2l[0]);
        atomicAdd(&sumsq[j0 + wn + 16 + lane], s2l[1]);
    }
}

__global__ void finalize_kernel(const float* __restrict__ sums, const float* __restrict__ sumsq,
                                const float* __restrict__ g, const float* __restrict__ be,
                                float* __restrict__ scale, float* __restrict__ shift, int C) {
    int t = threadIdx.x;
    if (t < C) {
        float mean = sums[t] * (1.0f / N_FINE);
        float var = sumsq[t] * (1.0f / N_FINE) - mean * mean;
        float sc = g[t] * rsqrtf(var + EPS_BN);
        scale[t] = sc;
        shift[t] = be[t] - mean * sc;
    }
}

// ---------------- BN2+ReLU fused transposed store: out[c][n] ----------------
__global__ __launch_bounds__(256) void out_kernel(const float* __restrict__ Y2,
                                                  const float* __restrict__ scale2,
                                                  const float* __restrict__ shift2,
                                                  float* __restrict__ out) {
    __shared__ float tile[64][65];
    int t = threadIdx.x;
    int n0 = blockIdx.x * 64, c0 = blockIdx.y * 64;
    int cl = t & 63, rg = t >> 6;
    #pragma unroll
    for (int i = 0; i < 16; i++) {
        int r = rg + i * 4;
        tile[r][cl] = Y2[(n0 + r) * C2 + c0 + cl];
    }
    __syncthreads();
    #pragma unroll
    for (int i = 0; i < 16; i++) {
        int c = rg + i * 4;
        float v = fmaf(tile[cl][c], scale2[c0 + c], shift2[c0 + c]);
        out[(c0 + c) * N_FINE + n0 + cl] = fmaxf(v, 0.f);
    }
}

extern "C" void kernel_launch(void* const* d_in, const int* in_sizes, int n_in,
                              void* d_out, int out_size, void* d_ws, size_t ws_size,
                              hipStream_t stream) {
    const float* fine_xyz   = (const float*)d_in[0];
    const float* coarse_xyz = (const float*)d_in[1];
    const int*   fine_pid   = (const int*)d_in[2];
    const int*   coarse_pid = (const int*)d_in[3];
    const float* fine_feat  = (const float*)d_in[4];
    const float* coarse_feat= (const float*)d_in[5];
    const float* W1  = (const float*)d_in[6];
    const float* b1  = (const float*)d_in[7];
    const float* g1  = (const float*)d_in[8];
    const float* be1 = (const float*)d_in[9];
    const float* W2  = (const float*)d_in[10];
    const float* b2  = (const float*)d_in[11];
    const float* g2  = (const float*)d_in[12];
    const float* be2 = (const float*)d_in[13];
    float* out = (float*)d_out;

    char* ws = (char*)d_ws;
    int*    ranges = (int*)(ws + OFF_RANGES);
    float*  sums1  = (float*)(ws + OFF_SUMS);
    float*  sumsq1 = sums1 + 256;
    float*  sums2  = sums1 + 512;
    float*  sumsq2 = sums1 + 640;
    float*  scale1 = (float*)(ws + OFF_SCALE1);
    float*  shift1 = (float*)(ws + OFF_SHIFT1);
    float*  scale2 = (float*)(ws + OFF_SCALE2);
    float*  shift2 = (float*)(ws + OFF_SHIFT2);
    float4* cpack  = (float4*)(ws + OFF_CPACK);
    float*  cfT    = (float*)(ws + OFF_CFT);
    int*    idx3   = (int*)(ws + OFF_IDX3);
    float*  w3     = (float*)(ws + OFF_W3);
    unsigned short* W1b = (unsigned short*)(ws + OFF_W1B);
    unsigned short* W2b = (unsigned short*)(ws + OFF_W2B);
    unsigned short* Y1  = (unsigned short*)(ws + OFF_Y1);
    float*          Y2  = (float*)(ws + OFF_Y2);

    setup_kernel<<<1361, 256, 0, stream>>>(coarse_pid, ranges, sums1,
                                           coarse_xyz, cpack, W1, W2, W1b, W2b,
                                           coarse_feat, cfT);
    knn_kernel<<<N_FINE / 4, 256, 0, stream>>>(fine_xyz, fine_pid, cpack, ranges, idx3, w3);

    gemm1_kernel<<<N_FINE / 32, 256, 0, stream>>>(idx3, w3, cfT, fine_feat,
                                                  W1b, b1, Y1, sums1, sumsq1);
    finalize_kernel<<<1, 256, 0, stream>>>(sums1, sumsq1, g1, be1, scale1, shift1, C1);

    mfma_gemm2_kernel<C1, C2><<<dim3(N_FINE / 64, C2 / 64), 256, 0, stream>>>(
        Y1, W2b, b2, scale1, shift1, Y2, sums2, sumsq2);
    finalize_kernel<<<1, 256, 0, stream>>>(sums2, sumsq2, g2, be2, scale2, shift2, C2);

    out_kernel<<<dim3(N_FINE / 64, C2 / 64), 256, 0, stream>>>(Y2, scale2, shift2, out);
}